// Round 1
// baseline (664.709 us; speedup 1.0000x reference)
//
#include <hip/hip_runtime.h>

#define BS 512
#define SRC 36
#define H 1024
#define MID 4096
#define M_ROWS (BS * SRC)   // 18432
#define ALPHAF 8.0f
#define GAMMAF 0.98f
#define EPSF 1e-6f

typedef __bf16 bf16;
typedef __attribute__((ext_vector_type(8))) __bf16 bf16x8;
typedef __attribute__((ext_vector_type(4))) __bf16 bf16x4;
typedef __attribute__((ext_vector_type(4))) float f32x4;

// ---------------- helpers ----------------
__device__ __forceinline__ float wave_reduce_sum(float v) {
    #pragma unroll
    for (int off = 32; off > 0; off >>= 1) v += __shfl_xor(v, off, 64);
    return v;
}

__device__ __forceinline__ void g2l16(const void* g, void* l) {
    __builtin_amdgcn_global_load_lds(
        (const __attribute__((address_space(1))) void*)g,
        (__attribute__((address_space(3))) void*)l,
        16, 0, 0);
}

// ---------------- sum(ru) ----------------
__global__ __launch_bounds__(256) void k_rusum(const float* __restrict__ ru,
                                               float* __restrict__ rusum) {
    int i = blockIdx.x * 256 + threadIdx.x;
    float v = ru[i];
    v = wave_reduce_sum(v);
    __shared__ float s[4];
    if ((threadIdx.x & 63) == 0) s[threadIdx.x >> 6] = v;
    __syncthreads();
    if (threadIdx.x == 0) atomicAdd(rusum, s[0] + s[1] + s[2] + s[3]);
}

// ---------------- gate: rg, ru_new, focal_att, ru_out, w ----------------
__global__ __launch_bounds__(64) void k_gate(const float* __restrict__ att,
                                             const float* __restrict__ ru,
                                             const float* __restrict__ rusum,
                                             float* __restrict__ w,
                                             float* __restrict__ ru_out) {
    int b = blockIdx.x;
    int s = threadIdx.x;   // 64 threads, 36 active
    float rg = 0.f, run = 0.f;
    if (s < SRC) {
        const float* row = att + ((size_t)b * SRC + s) * SRC;
        #pragma unroll
        for (int j = 0; j < SRC; ++j) rg += row[j];
        float scale = (*rusum == 0.0f) ? 1.0f : (1.0f / (1.0f + GAMMAF));
        run = (ru[b * SRC + s] * GAMMAF + rg) * scale;
    }
    float sa = (s < SRC) ? sqrtf(run) : 0.f;
    float S = wave_reduce_sum(sa);
    float T = wave_reduce_sum(run * sa);
    if (s < SRC) {
        float funcF = run * S - T;
        float aw = (funcF > 0.f) ? ALPHAF : (1.0f / ALPHAF);
        ru_out[b * SRC + s] = aw * run;
        w[b * SRC + s] = aw * rg;
    }
}

// ---------------- transpose f32 [rows][cols] -> bf16 [cols][rows] ----------------
__global__ __launch_bounds__(256) void k_transpose_bf16(const float* __restrict__ in,
                                                        bf16* __restrict__ out,
                                                        int rows, int cols) {
    __shared__ float tile[32][33];
    int bx = blockIdx.x * 32, by = blockIdx.y * 32;
    int tx = threadIdx.x;
    #pragma unroll
    for (int j = threadIdx.y; j < 32; j += 8)
        tile[j][tx] = in[(size_t)(by + j) * cols + bx + tx];
    __syncthreads();
    #pragma unroll
    for (int j = threadIdx.y; j < 32; j += 8)
        out[(size_t)(bx + j) * rows + by + tx] = (bf16)tile[tx][j];
}

// ---------------- LN1 fused with w-scale -> mm (bf16) ----------------
__global__ __launch_bounds__(256) void k_ln1(const f32x4* __restrict__ v,
                                             const f32x4* __restrict__ q,
                                             const f32x4* __restrict__ g1,
                                             const f32x4* __restrict__ b1,
                                             const float* __restrict__ w,
                                             bf16x4* __restrict__ mm) {
    int row = blockIdx.x, t = threadIdx.x;
    size_t i = (size_t)row * 256 + t;
    f32x4 x = v[i];
    f32x4 y = q[i];
    x.x += y.x; x.y += y.y; x.z += y.z; x.w += y.w;
    float sum = x.x + x.y + x.z + x.w;
    float sq  = x.x * x.x + x.y * x.y + x.z * x.z + x.w * x.w;
    sum = wave_reduce_sum(sum);
    sq  = wave_reduce_sum(sq);
    __shared__ float ss[4], s2[4];
    if ((t & 63) == 0) { ss[t >> 6] = sum; s2[t >> 6] = sq; }
    __syncthreads();
    sum = ss[0] + ss[1] + ss[2] + ss[3];
    sq  = s2[0] + s2[1] + s2[2] + s2[3];
    float mu  = sum * (1.0f / H);
    float var = sq * (1.0f / H) - mu * mu;
    float inv = rsqrtf(var + EPSF);
    float ww = w[row];
    f32x4 g = g1[t], b = b1[t];
    bf16x4 o;
    o.x = (bf16)(ww * ((x.x - mu) * inv * g.x + b.x));
    o.y = (bf16)(ww * ((x.y - mu) * inv * g.y + b.y));
    o.z = (bf16)(ww * ((x.z - mu) * inv * g.z + b.z));
    o.w = (bf16)(ww * ((x.w - mu) * inv * g.w + b.w));
    mm[i] = o;
}

// ---------------- LN2: out = LN(mm + fc), in place over d_out ----------------
__global__ __launch_bounds__(256) void k_ln2(float* __restrict__ out,
                                             const bf16x4* __restrict__ mm,
                                             const f32x4* __restrict__ g2,
                                             const f32x4* __restrict__ b2) {
    int row = blockIdx.x, t = threadIdx.x;
    size_t i = (size_t)row * 256 + t;
    f32x4* outv = (f32x4*)out;
    f32x4 x = outv[i];
    bf16x4 m = mm[i];
    x.x += (float)m.x; x.y += (float)m.y; x.z += (float)m.z; x.w += (float)m.w;
    float sum = x.x + x.y + x.z + x.w;
    float sq  = x.x * x.x + x.y * x.y + x.z * x.z + x.w * x.w;
    sum = wave_reduce_sum(sum);
    sq  = wave_reduce_sum(sq);
    __shared__ float ss[4], s2[4];
    if ((t & 63) == 0) { ss[t >> 6] = sum; s2[t >> 6] = sq; }
    __syncthreads();
    sum = ss[0] + ss[1] + ss[2] + ss[3];
    sq  = s2[0] + s2[1] + s2[2] + s2[3];
    float mu  = sum * (1.0f / H);
    float var = sq * (1.0f / H) - mu * mu;
    float inv = rsqrtf(var + EPSF);
    f32x4 g = g2[t], b = b2[t];
    f32x4 o;
    o.x = (x.x - mu) * inv * g.x + b.x;
    o.y = (x.y - mu) * inv * g.y + b.y;
    o.z = (x.z - mu) * inv * g.z + b.z;
    o.w = (x.w - mu) * inv * g.w + b.w;
    outv[i] = o;
}

// ---------------- bf16 MFMA GEMM: C[M,N] = A[M,K] * Bt[N,K]^T + bias ----------------
// 128x128 tile, BK=32, 256 threads (4 waves, each 64x64 via 4x4 of 16x16x32).
template<int N, int K, bool RELU, bool BF16OUT>
__global__ __launch_bounds__(256) void k_gemm(const bf16* __restrict__ A,
                                              const bf16* __restrict__ Bt,
                                              const float* __restrict__ bias,
                                              void* __restrict__ C) {
    __shared__ bf16 sA[128 * 32];
    __shared__ bf16 sB[128 * 32];
    const int tid  = threadIdx.x;
    const int lane = tid & 63;
    const int wave = tid >> 6;
    const int quad = lane >> 4;
    const int l16  = lane & 15;
    const size_t bm = (size_t)blockIdx.y * 128;
    const size_t bn = (size_t)blockIdx.x * 128;
    const int wm = (wave & 1) * 64;
    const int wn = (wave >> 1) * 64;

    f32x4 acc[4][4] = {};

    // staging: tile is [128 rows][32 k] bf16 = 8 KB = 8 chunks of 1 KB.
    // wave handles chunks {2w, 2w+1} of both A and B.
    // chunk c covers rows 16c..16c+15; lane l -> row 16c + (l>>2), k-off (l&3)*8.
    const int c0 = 2 * wave, c1 = 2 * wave + 1;
    const int r4 = lane >> 2, k8 = (lane & 3) * 8;

    const bf16* gA0 = A  + (bm + 16 * c0 + r4) * (size_t)K + k8;
    const bf16* gA1 = A  + (bm + 16 * c1 + r4) * (size_t)K + k8;
    const bf16* gB0 = Bt + (bn + 16 * c0 + r4) * (size_t)K + k8;
    const bf16* gB1 = Bt + (bn + 16 * c1 + r4) * (size_t)K + k8;
    bf16* lA0 = sA + c0 * 512 + lane * 8;
    bf16* lA1 = sA + c1 * 512 + lane * 8;
    bf16* lB0 = sB + c0 * 512 + lane * 8;
    bf16* lB1 = sB + c1 * 512 + lane * 8;

    for (int k0 = 0; k0 < K; k0 += 32) {
        g2l16(gA0 + k0, lA0);
        g2l16(gA1 + k0, lA1);
        g2l16(gB0 + k0, lB0);
        g2l16(gB1 + k0, lB1);
        __syncthreads();   // drains vmcnt -> staging visible

        bf16x8 af[4], bfr[4];
        #pragma unroll
        for (int mi = 0; mi < 4; ++mi)
            af[mi] = *(const bf16x8*)(sA + (wm + mi * 16 + l16) * 32 + quad * 8);
        #pragma unroll
        for (int ni = 0; ni < 4; ++ni)
            bfr[ni] = *(const bf16x8*)(sB + (wn + ni * 16 + l16) * 32 + quad * 8);
        #pragma unroll
        for (int mi = 0; mi < 4; ++mi)
            #pragma unroll
            for (int ni = 0; ni < 4; ++ni)
                acc[mi][ni] = __builtin_amdgcn_mfma_f32_16x16x32_bf16(
                    af[mi], bfr[ni], acc[mi][ni], 0, 0, 0);
        __syncthreads();   // all waves done reading before restage
    }

    // epilogue: D row = quad*4+reg, col = l16 within each 16x16 tile
    #pragma unroll
    for (int mi = 0; mi < 4; ++mi) {
        #pragma unroll
        for (int reg = 0; reg < 4; ++reg) {
            size_t row = bm + wm + mi * 16 + quad * 4 + reg;
            #pragma unroll
            for (int ni = 0; ni < 4; ++ni) {
                int col = wn + ni * 16 + l16;
                float val = acc[mi][ni][reg] + bias[bn + col];
                if (RELU) val = fmaxf(val, 0.f);
                if (BF16OUT) ((bf16*)C)[row * N + bn + col] = (bf16)val;
                else         ((float*)C)[row * N + bn + col] = val;
            }
        }
    }
}

extern "C" void kernel_launch(void* const* d_in, const int* in_sizes, int n_in,
                              void* d_out, int out_size, void* d_ws, size_t ws_size,
                              hipStream_t stream) {
    (void)in_sizes; (void)n_in; (void)out_size; (void)ws_size;
    const float* v   = (const float*)d_in[0];
    const float* q   = (const float*)d_in[1];
    const float* att = (const float*)d_in[2];
    const float* ru  = (const float*)d_in[3];
    const float* g1  = (const float*)d_in[4];
    const float* b1  = (const float*)d_in[5];
    const float* g2  = (const float*)d_in[6];
    const float* b2  = (const float*)d_in[7];
    const float* W1  = (const float*)d_in[8];
    const float* c1  = (const float*)d_in[9];
    const float* W2  = (const float*)d_in[10];
    const float* c2  = (const float*)d_in[11];

    float* out    = (float*)d_out;
    float* ru_out = out + (size_t)M_ROWS * H;

    char* ws = (char*)d_ws;
    float* rusum = (float*)ws;
    float* w     = (float*)(ws + 256);
    size_t off = 256 + (size_t)M_ROWS * sizeof(float);
    off = (off + 255) & ~(size_t)255;
    bf16* mm  = (bf16*)(ws + off); off += (size_t)M_ROWS * H * 2;
    bf16* W1t = (bf16*)(ws + off); off += (size_t)H * MID * 2;
    bf16* W2t = (bf16*)(ws + off); off += (size_t)H * MID * 2;
    bf16* h   = (bf16*)(ws + off); off += (size_t)M_ROWS * MID * 2;

    hipMemsetAsync(rusum, 0, sizeof(float), stream);
    k_rusum<<<M_ROWS / 256, 256, 0, stream>>>(ru, rusum);
    k_gate<<<BS, 64, 0, stream>>>(att, ru, rusum, w, ru_out);
    k_transpose_bf16<<<dim3(MID / 32, H / 32), dim3(32, 8), 0, stream>>>(W1, W1t, H, MID);
    k_transpose_bf16<<<dim3(H / 32, MID / 32), dim3(32, 8), 0, stream>>>(W2, W2t, MID, H);
    k_ln1<<<M_ROWS, 256, 0, stream>>>((const f32x4*)v, (const f32x4*)q,
                                      (const f32x4*)g1, (const f32x4*)b1, w, (bf16x4*)mm);
    k_gemm<MID, H, true, true><<<dim3(MID / 128, M_ROWS / 128), 256, 0, stream>>>(mm, W1t, c1, h);
    k_gemm<H, MID, false, false><<<dim3(H / 128, M_ROWS / 128), 256, 0, stream>>>(h, W2t, c2, out);
    k_ln2<<<M_ROWS, 256, 0, stream>>>(out, (const bf16x4*)mm, (const f32x4*)g2, (const f32x4*)b2);
}